// Round 14
// baseline (374.482 us; speedup 1.0000x reference)
//
#include <hip/hip_runtime.h>

#define CAP 64  // max in-degree slots per node (deg ~ Poisson(20); P(>64) ~ 1e-14)

typedef __attribute__((ext_vector_type(8))) short bf16x8;
typedef __attribute__((ext_vector_type(4))) float f32x4;

__device__ __forceinline__ float sigf(float x) {
    return __builtin_amdgcn_rcpf(1.0f + __expf(-x));
}
__device__ __forceinline__ float tanhfast(float x) {
    return 2.0f * __builtin_amdgcn_rcpf(1.0f + __expf(-2.0f * x)) - 1.0f;
}
__device__ __forceinline__ short bfr(float f) {          // fp32 -> bf16 RNE
    unsigned u = __float_as_uint(f);
    unsigned r = (u + 0x7FFFu + ((u >> 16) & 1u)) >> 16;
    return (short)r;
}
__device__ __forceinline__ float bf2f(unsigned short u) {
    return __uint_as_float(((unsigned)u) << 16);
}
__device__ __forceinline__ bf16x8 cvt8(const float* p) { // 8 contiguous fp32 -> bf16x8
    const float4* q = (const float4*)p;
    float4 u = q[0], v = q[1];
    bf16x8 r;
    r[0]=bfr(u.x); r[1]=bfr(u.y); r[2]=bfr(u.z); r[3]=bfr(u.w);
    r[4]=bfr(v.x); r[5]=bfr(v.y); r[6]=bfr(v.z); r[7]=bfr(v.w);
    return r;
}

// ---------------- weight conversion (fragment order, bias K-folded) + cnt zeroing ----------------
__global__ void convert_kernel(
    const float* __restrict__ Whh_n, const float* __restrict__ Wih_n,
    const float* __restrict__ bih_n, const float* __restrict__ bhh_n,
    const float* __restrict__ Whh_e, const float* __restrict__ Wih_e,
    const float* __restrict__ bih_e, const float* __restrict__ bhh_e,
    const float* __restrict__ Wgat,
    unsigned short* __restrict__ WnF, unsigned short* __restrict__ WeF,
    unsigned short* __restrict__ WgF, int* __restrict__ cnt, int N)
{
    int i = blockIdx.x * 256 + threadIdx.x;
    if (i < N) cnt[i] = 0;                       // replaces hipMemsetAsync
    if (i < 512 * 160) {                         // node: tp 0..31, k4 0..4 (K=160)
        int j = i & 7, unit = i >> 3;
        int lane = unit & 63, tk = unit >> 6;
        int tp = tk / 5, k4 = tk - tp * 5;
        int r = (tp & 3) * 128 + (tp >> 2) * 16 + (lane & 15);   // u-repacked row
        int k = k4 * 32 + (lane >> 4) * 8 + j;
        float v = (k < 128) ? Whh_n[r * 128 + k]
                : (k < 133) ? Wih_n[r * 5 + (k - 128)]
                : (k == 133) ? (bih_n[r] + bhh_n[r]) : 0.f;
        WnF[i] = (unsigned short)bfr(v);
    }
    if (i < 128 * 64) {                          // edge: t 0..7, s 0..1 (K=64)
        int j = i & 7, unit = i >> 3;
        int lane = unit & 63, ts = unit >> 6;
        int t = ts >> 1, s = ts & 1;
        int r = t * 16 + (lane & 15);
        int k = s * 32 + (lane >> 4) * 8 + j;
        float v = (k < 32) ? Whh_e[r * 32 + k]
                : (k < 34) ? Wih_e[r * 2 + (k - 32)]
                : (k == 34) ? (bih_e[r] + bhh_e[r]) : 0.f;
        WeF[i] = (unsigned short)bfr(v);
    }
    if (i < 64 * 160) {                          // gat (W^T): t 0..3, k4 0..4
        int j = i & 7, unit = i >> 3;
        int lane = unit & 63, tk = unit >> 6;
        int t = tk / 5, k4 = tk - t * 5;
        int r = t * 16 + (lane & 15);
        int k = k4 * 32 + (lane >> 4) * 8 + j;
        WgF[i] = (unsigned short)bfr(Wgat[k * 64 + r]);
    }
}

// ---------------- capped per-dst slot list build: stores (edge, src) pairs ----------------
__global__ void csr_fill_kernel(const int* __restrict__ src, const int* __restrict__ dst,
                                int* __restrict__ cnt, int2* __restrict__ eidp, int E)
{
    int e = blockIdx.x * blockDim.x + threadIdx.x;
    if (e >= E) return;
    int d = dst[e];
    int s = src[e];
    int k = atomicAdd(cnt + d, 1);
    if (k < CAP) eidp[(size_t)d * CAP + k] = make_int2(e, s);
}

// ---------------- edge LSTM v5: packed linear streams + persistent grid-stride pipeline ----------------
__global__ __launch_bounds__(256, 3) void edge_lstm_mfma(
    const float* __restrict__ eattr, const float* __restrict__ h_in, const float* __restrict__ c_in,
    const unsigned short* __restrict__ WeF,
    float* __restrict__ he_out, float* __restrict__ ce_out, int E)
{
    __shared__ float Gall[4][16 * 132];              // per-wave gate buffer [edge][128] (+pad)
    __shared__ unsigned short Hall[4][16 * 40];      // per-wave bf16 h tile, row stride 40
    const int lane = threadIdx.x & 63, wave = threadIdx.x >> 6;
    const int lr = lane & 15, lg = lane >> 4;
    const int T = E >> 4;                            // E % 16 == 0
    const int nwaves = gridDim.x * 4;
    const int wid = blockIdx.x * 4 + wave;
    if (wid >= T) return;
    float* G = Gall[wave];
    unsigned short* H = Hall[wave];

    const bf16x8* Wv = (const bf16x8*)WeF;
    bf16x8 wa0[8], wa1[8];
    #pragma unroll
    for (int t = 0; t < 8; ++t) {
        wa0[t] = Wv[(t * 2 + 0) * 64 + lane];
        wa1[t] = Wv[(t * 2 + 1) * 64 + lane];
    }

    f32x4 phA, phB, pcA, pcB; float pea0 = 0.f, pea1 = 0.f;
    {
        const size_t dwb = (size_t)wid * 512;
        phA = *(const f32x4*)(h_in + dwb + lane * 4);
        phB = *(const f32x4*)(h_in + dwb + 256 + lane * 4);
        pcA = *(const f32x4*)(c_in + dwb + lane * 4);
        pcB = *(const f32x4*)(c_in + dwb + 256 + lane * 4);
        if (lg == 0) {
            pea0 = eattr[(size_t)(wid * 16 + lr) * 2];
            pea1 = eattr[(size_t)(wid * 16 + lr) * 2 + 1];
        }
    }

    for (int t = wid; t < T; t += nwaves) {
        const f32x4 hA = phA, hB = phB, cA = pcA, cB = pcB;
        const float ea0 = pea0, ea1 = pea1;
        const size_t dwbase = (size_t)t * 512;
        const int tn = t + nwaves;
        if (tn < T) {                                // issue next tile's loads NOW
            const size_t dwb = (size_t)tn * 512;
            phA = *(const f32x4*)(h_in + dwb + lane * 4);
            phB = *(const f32x4*)(h_in + dwb + 256 + lane * 4);
            pcA = *(const f32x4*)(c_in + dwb + lane * 4);
            pcB = *(const f32x4*)(c_in + dwb + 256 + lane * 4);
            if (lg == 0) {
                pea0 = eattr[(size_t)(tn * 16 + lr) * 2];
                pea1 = eattr[(size_t)(tn * 16 + lr) * 2 + 1];
            }
        }

        {
            const int e = lane >> 3, c4 = (lane & 7) * 4;
            ushort4 pa, pb;
            pa.x = (unsigned short)bfr(hA[0]); pa.y = (unsigned short)bfr(hA[1]);
            pa.z = (unsigned short)bfr(hA[2]); pa.w = (unsigned short)bfr(hA[3]);
            pb.x = (unsigned short)bfr(hB[0]); pb.y = (unsigned short)bfr(hB[1]);
            pb.z = (unsigned short)bfr(hB[2]); pb.w = (unsigned short)bfr(hB[3]);
            *(ushort4*)(H + e * 40 + c4)       = pa;     // rows 0-7
            *(ushort4*)(H + (8 + e) * 40 + c4) = pb;     // rows 8-15
        }
        bf16x8 b0 = *(const bf16x8*)(H + lr * 40 + lg * 8);
        bf16x8 b1 = {0,0,0,0,0,0,0,0};
        if (lg == 0) {                               // k=32,33 -> eattr; k=34 -> 1 (bias col)
            b1[0] = bfr(ea0); b1[1] = bfr(ea1); b1[2] = (short)0x3F80;
        }

        f32x4 acc[8];
        #pragma unroll
        for (int tt = 0; tt < 8; ++tt) {
            f32x4 v = {0, 0, 0, 0};
            v = __builtin_amdgcn_mfma_f32_16x16x32_bf16(wa0[tt], b0, v, 0, 0, 0);
            v = __builtin_amdgcn_mfma_f32_16x16x32_bf16(wa1[tt], b1, v, 0, 0, 0);
            acc[tt] = v;
        }

        #pragma unroll
        for (int u = 0; u < 8; ++u) {
            const int col = (u >> 1) * 32 + (u & 1) * 16 + lg * 4;
            *(f32x4*)(G + lr * 132 + col) = acc[u];
        }

        const int e = lane >> 3, jq = (lane & 7) * 4;
        #pragma unroll
        for (int part = 0; part < 2; ++part) {
            const float* gr = G + (part * 8 + e) * 132;
            const f32x4 gi = *(const f32x4*)(gr + jq);
            const f32x4 gf = *(const f32x4*)(gr + 32 + jq);
            const f32x4 gg = *(const f32x4*)(gr + 64 + jq);
            const f32x4 go = *(const f32x4*)(gr + 96 + jq);
            const f32x4 cold = part ? cB : cA;
            f32x4 cres, hres;
            #pragma unroll
            for (int q = 0; q < 4; ++q) {
                float c2 = sigf(gf[q]) * cold[q] + sigf(gi[q]) * tanhfast(gg[q]);
                cres[q] = c2;
                hres[q] = sigf(go[q]) * tanhfast(c2);
            }
            __builtin_nontemporal_store(cres, (f32x4*)(ce_out + dwbase + part * 256 + lane * 4));
            *(f32x4*)(he_out + dwbase + part * 256 + lane * 4) = hres;   // re-read by enc gather
        }
    }
}

// ========== fused node LSTM + edge_enc + GAT linear: block = 64 nodes, wave = 16 ==========
// phase 0: node LSTM (u-repacked); hn/cn nontemporal; h2 rows stashed bf16 in LDS
// phase A: scatter-mean enc gather into LDS (wave-private, no barrier)
// phase B: [hn|enc] @ Wgat from LDS; xl stored bf16; logits via butterfly
__global__ __launch_bounds__(256) void node_enc_gatxl_kernel(
    const float* __restrict__ x, const float* __restrict__ h_in, const float* __restrict__ c_in,
    const unsigned short* __restrict__ WnF,
    float* __restrict__ hn_out, float* __restrict__ cn_out,
    const int* __restrict__ cnt, const int2* __restrict__ eidp, const float* __restrict__ he,
    const unsigned short* __restrict__ WgF,
    const float* __restrict__ attS, const float* __restrict__ attD,
    unsigned short* __restrict__ xlb, float* __restrict__ asrc, float* __restrict__ adst, int N)
{
    __shared__ unsigned short hball[4][16 * 136];    // bf16 h2 rows, stride 136 (16B-aligned rows)
    __shared__ float encs[64 * 36];                  // row stride 36: 2-way max bank alias
    const int lane = threadIdx.x & 63, wave = threadIdx.x >> 6;
    const int nbase = blockIdx.x * 64 + wave * 16;
    if (nbase >= N) return;                          // N % 16 == 0 -> wave-uniform
    unsigned short* H = hball[wave];
    const int lr = lane & 15, lg = lane >> 4;
    const int node = nbase + lr;

    // ---- phase 0: node LSTM ----
    {
        bf16x8 b[5];
        const float* hp = h_in + (size_t)node * 128 + lg * 8;
        b[0] = cvt8(hp); b[1] = cvt8(hp + 32); b[2] = cvt8(hp + 64); b[3] = cvt8(hp + 96);
        bf16x8 bx = {0,0,0,0,0,0,0,0};
        if (lg == 0) {                               // k=128..132 -> x; k=133 -> 1 (bias col)
            const float* xp = x + (size_t)node * 5;
            bx[0]=bfr(xp[0]); bx[1]=bfr(xp[1]); bx[2]=bfr(xp[2]); bx[3]=bfr(xp[3]); bx[4]=bfr(xp[4]);
            bx[5] = (short)0x3F80;
        }
        b[4] = bx;
        const bf16x8* Wv = (const bf16x8*)WnF;
        #pragma unroll
        for (int u = 0; u < 8; ++u) {                // 4 live accumulators per u-block
            f32x4 acc[4];
            #pragma unroll
            for (int g = 0; g < 4; ++g) {
                const bf16x8* ap = Wv + (u * 4 + g) * 320 + lane;
                f32x4 v = {0, 0, 0, 0};
                #pragma unroll
                for (int k4 = 0; k4 < 5; ++k4)
                    v = __builtin_amdgcn_mfma_f32_16x16x32_bf16(ap[k4 * 64], b[k4], v, 0, 0, 0);
                acc[g] = v;
            }
            const int jb = u * 16 + lg * 4;
            f32x4 cold = *(const f32x4*)(c_in + (size_t)node * 128 + jb);
            f32x4 cres, hres;
            #pragma unroll
            for (int q = 0; q < 4; ++q) {
                float c2 = sigf(acc[1][q]) * cold[q] + sigf(acc[0][q]) * tanhfast(acc[2][q]);
                cres[q] = c2;
                hres[q] = sigf(acc[3][q]) * tanhfast(c2);
            }
            __builtin_nontemporal_store(cres, (f32x4*)(cn_out + (size_t)node * 128 + jb));
            __builtin_nontemporal_store(hres, (f32x4*)(hn_out + (size_t)node * 128 + jb));
            ushort4 hh;                              // stash bf16 row chunk in LDS for phase B
            hh.x = (unsigned short)bfr(hres[0]); hh.y = (unsigned short)bfr(hres[1]);
            hh.z = (unsigned short)bfr(hres[2]); hh.w = (unsigned short)bfr(hres[3]);
            *(ushort4*)(H + lr * 136 + jb) = hh;
        }
    }

    // ---- phase A: lanes 0-31 -> node t, lanes 32-63 -> node t+1 ----
    const int half = lane >> 5, hl = lane & 31;
    const int g4 = hl >> 3, l8 = hl & 7;             // 4 groups x 8 lanes x float4
    for (int t = 0; t < 16; t += 2) {
        const int nd = nbase + t + half;
        const int c = cnt[nd];
        const int m = min(c, CAP);
        const int2* el = eidp + (size_t)nd * CAP;
        f32x4 acc = {0, 0, 0, 0};
        for (int i = g4; i < m; i += 4)
            acc += *(const f32x4*)(he + (size_t)el[i].x * 32 + l8 * 4);
        #pragma unroll
        for (int off = 8; off <= 16; off <<= 1) {    // reduce within 32-lane half
            acc[0] += __shfl_xor(acc[0], off);
            acc[1] += __shfl_xor(acc[1], off);
            acc[2] += __shfl_xor(acc[2], off);
            acc[3] += __shfl_xor(acc[3], off);
        }
        if (g4 == 0) {
            float inv = 1.0f / fmaxf((float)c, 1.0f);
            f32x4 r; r[0]=acc[0]*inv; r[1]=acc[1]*inv; r[2]=acc[2]*inv; r[3]=acc[3]*inv;
            *(f32x4*)(&encs[(wave * 16 + t + half) * 36 + l8 * 4]) = r;
        }
    }

    // ---- phase B (same wave; LDS-sourced fragments; no __syncthreads) ----
    bf16x8 b[5];
    b[0] = *(const bf16x8*)(H + lr * 136 + lg * 8);
    b[1] = *(const bf16x8*)(H + lr * 136 + 32 + lg * 8);
    b[2] = *(const bf16x8*)(H + lr * 136 + 64 + lg * 8);
    b[3] = *(const bf16x8*)(H + lr * 136 + 96 + lg * 8);
    b[4] = cvt8(&encs[(wave * 16 + lr) * 36 + lg * 8]);
    const bf16x8* Wv = (const bf16x8*)WgF;
    #pragma unroll
    for (int t = 0; t < 4; ++t) {                    // t = head
        const bf16x8* ap = Wv + t * 320 + lane;
        f32x4 v = {0, 0, 0, 0};
        #pragma unroll
        for (int k4 = 0; k4 < 5; ++k4)
            v = __builtin_amdgcn_mfma_f32_16x16x32_bf16(ap[k4 * 64], b[k4], v, 0, 0, 0);
        ushort4 pk;
        pk.x = (unsigned short)bfr(v[0]); pk.y = (unsigned short)bfr(v[1]);
        pk.z = (unsigned short)bfr(v[2]); pk.w = (unsigned short)bfr(v[3]);
        *(ushort4*)(xlb + (size_t)node * 64 + t * 16 + lg * 4) = pk;
        const f32x4 ws = *(const f32x4*)(attS + t * 16 + lg * 4);
        const f32x4 wd = *(const f32x4*)(attD + t * 16 + lg * 4);
        float p1 = v[0]*ws[0] + v[1]*ws[1] + v[2]*ws[2] + v[3]*ws[3];
        float p2 = v[0]*wd[0] + v[1]*wd[1] + v[2]*wd[2] + v[3]*wd[3];
        p1 += __shfl_xor(p1, 16); p2 += __shfl_xor(p2, 16);
        p1 += __shfl_xor(p1, 32); p2 += __shfl_xor(p2, 32);
        if (lg == 0) {
            asrc[(size_t)node * 4 + t] = p1;
            adst[(size_t)node * 4 + t] = p2;
        }
    }
}

// ---------------- fused GAT softmax + aggregation: one wave per node, bf16 xl ----------------
__global__ __launch_bounds__(256) void gat_node_kernel(
    const int* __restrict__ cnt, const int2* __restrict__ eidp,
    const float* __restrict__ asrc, const float* __restrict__ adst,
    const unsigned short* __restrict__ xlb, const float* __restrict__ bias,
    float* __restrict__ out, int N)
{
    const int wid = (blockIdx.x * blockDim.x + threadIdx.x) >> 6;
    const int lane = threadIdx.x & 63;
    if (wid >= N) return;
    const int n = wid;
    const int m = min(cnt[n], CAP);
    const int h = lane >> 4, c16 = lane & 15;
    const int nslot = (m + 15) >> 4;             // <= 4
    const float ad = adst[n * 4 + h];
    float aself = asrc[n * 4 + h] + ad;
    aself = aself > 0.f ? aself : 0.2f * aself;
    const int2* el = eidp + (size_t)n * CAP;
    int   ss[4];
    float aa[4];
    float mx = aself;
    #pragma unroll
    for (int k = 0; k < 4; ++k) {
        if (k >= nslot) break;
        int i = k * 16 + c16;
        if (i < m) {
            int s = el[i].y;                     // src directly from slot pair
            float a = asrc[s * 4 + h] + ad;
            a = a > 0.f ? a : 0.2f * a;
            ss[k] = s; aa[k] = a;
            mx = fmaxf(mx, a);
        } else { ss[k] = 0; aa[k] = -1e30f; }
    }
    #pragma unroll
    for (int off = 1; off < 16; off <<= 1) mx = fmaxf(mx, __shfl_xor(mx, off));
    float ea[4];
    float p = 0.f;
    #pragma unroll
    for (int k = 0; k < 4; ++k) {
        if (k >= nslot) break;
        ea[k] = __expf(aa[k] - mx);
        p += ea[k];
    }
    #pragma unroll
    for (int off = 1; off < 16; off <<= 1) p += __shfl_xor(p, off);
    float eself = __expf(aself - mx);
    float sacc = eself + p;
    float oacc = eself * bf2f(xlb[(size_t)n * 64 + lane]);
    const int grp = lane & 48;
    #pragma unroll
    for (int k = 0; k < 4; ++k) {
        if (k >= nslot) break;
        const int lim = min(16, m - k * 16);
        #pragma unroll 4
        for (int cc = 0; cc < lim; ++cc) {
            int srcl = grp | cc;
            float w = __shfl(ea[k], srcl);
            int   s = __shfl(ss[k], srcl);
            oacc += w * bf2f(xlb[(size_t)s * 64 + lane]);
        }
    }
    float r = oacc / sacc;
    r += __shfl_xor(r, 16);                      // head mean
    r += __shfl_xor(r, 32);
    if (lane < 16) out[(size_t)n * 16 + lane] = 0.25f * r + bias[lane];
}

extern "C" void kernel_launch(void* const* d_in, const int* in_sizes, int n_in,
                              void* d_out, int out_size, void* d_ws, size_t ws_size,
                              hipStream_t stream)
{
    const float* x     = (const float*)d_in[0];
    const int*   ei    = (const int*)  d_in[1];
    const float* eattr = (const float*)d_in[2];
    const float* hn_h  = (const float*)d_in[3];
    const float* hn_c  = (const float*)d_in[4];
    const float* he_h  = (const float*)d_in[5];
    const float* he_c  = (const float*)d_in[6];
    const float* Wih_n = (const float*)d_in[7];
    const float* Whh_n = (const float*)d_in[8];
    const float* bih_n = (const float*)d_in[9];
    const float* bhh_n = (const float*)d_in[10];
    const float* Wih_e = (const float*)d_in[11];
    const float* Whh_e = (const float*)d_in[12];
    const float* bih_e = (const float*)d_in[13];
    const float* bhh_e = (const float*)d_in[14];
    const float* W_gat = (const float*)d_in[15];
    const float* attS  = (const float*)d_in[16];
    const float* attD  = (const float*)d_in[17];
    const float* biasG = (const float*)d_in[18];

    const int N = in_sizes[0] / 5;
    const int E = in_sizes[2] / 2;

    float* out = (float*)d_out;
    float* hn  = out + (size_t)N * 16;
    float* cn  = hn  + (size_t)N * 128;
    float* he  = cn  + (size_t)N * 128;
    float* ce  = he  + (size_t)E * 32;

    char* p = (char*)d_ws;
    size_t off = 0;
    auto take = [&](size_t bytes) -> void* {
        void* r = p + off;
        off = (off + bytes + 255) & ~(size_t)255;
        return r;
    };
    int*   cnt  = (int*)  take((size_t)N * 4);
    int2*  eidp = (int2*) take((size_t)N * CAP * 8);
    unsigned short* xlb = (unsigned short*)take((size_t)N * 64 * 2);
    float* asrc = (float*)take((size_t)N * 4 * 4);
    float* adst = (float*)take((size_t)N * 4 * 4);
    unsigned short* WnF = (unsigned short*)take(512 * 160 * 2);
    unsigned short* WeF = (unsigned short*)take(128 * 64 * 2);
    unsigned short* WgF = (unsigned short*)take(64 * 160 * 2);

    convert_kernel<<<(512 * 160 + 255) / 256, 256, 0, stream>>>(
        Whh_n, Wih_n, bih_n, bhh_n, Whh_e, Wih_e, bih_e, bhh_e, W_gat,
        WnF, WeF, WgF, cnt, N);
    csr_fill_kernel<<<(E + 255) / 256, 256, 0, stream>>>(ei, ei + E, cnt, eidp, E);
    edge_lstm_mfma<<<768, 256, 0, stream>>>(
        eattr, he_h, he_c, WeF, he, ce, E);
    node_enc_gatxl_kernel<<<(N + 63) / 64, 256, 0, stream>>>(
        x, hn_h, hn_c, WnF, hn, cn,
        cnt, eidp, he, WgF, attS, attD, xlb, asrc, adst, N);
    gat_node_kernel<<<(N + 3) / 4, 256, 0, stream>>>(
        cnt, eidp, asrc, adst, xlb, biasG, out, N);
}

// Round 15
// 349.802 us; speedup vs baseline: 1.0706x; 1.0706x over previous
//
#include <hip/hip_runtime.h>

#define CAP 64  // max in-degree slots per node (deg ~ Poisson(20); P(>64) ~ 1e-14)

typedef __attribute__((ext_vector_type(8))) short bf16x8;
typedef __attribute__((ext_vector_type(4))) float f32x4;

__device__ __forceinline__ float sigf(float x) {
    return __builtin_amdgcn_rcpf(1.0f + __expf(-x));
}
__device__ __forceinline__ float tanhfast(float x) {
    return 2.0f * __builtin_amdgcn_rcpf(1.0f + __expf(-2.0f * x)) - 1.0f;
}
__device__ __forceinline__ short bfr(float f) {          // fp32 -> bf16 RNE
    unsigned u = __float_as_uint(f);
    unsigned r = (u + 0x7FFFu + ((u >> 16) & 1u)) >> 16;
    return (short)r;
}
__device__ __forceinline__ float bf2f(unsigned short u) {
    return __uint_as_float(((unsigned)u) << 16);
}
__device__ __forceinline__ bf16x8 cvt8(const float* p) { // 8 contiguous fp32 -> bf16x8
    const float4* q = (const float4*)p;
    float4 u = q[0], v = q[1];
    bf16x8 r;
    r[0]=bfr(u.x); r[1]=bfr(u.y); r[2]=bfr(u.z); r[3]=bfr(u.w);
    r[4]=bfr(v.x); r[5]=bfr(v.y); r[6]=bfr(v.z); r[7]=bfr(v.w);
    return r;
}

// ---------------- weight conversion (fragment order, bias K-folded) + cnt zeroing ----------------
__global__ void convert_kernel(
    const float* __restrict__ Whh_n, const float* __restrict__ Wih_n,
    const float* __restrict__ bih_n, const float* __restrict__ bhh_n,
    const float* __restrict__ Whh_e, const float* __restrict__ Wih_e,
    const float* __restrict__ bih_e, const float* __restrict__ bhh_e,
    const float* __restrict__ Wgat,
    unsigned short* __restrict__ WnF, unsigned short* __restrict__ WeF,
    unsigned short* __restrict__ WgF, int* __restrict__ cnt, int N)
{
    int i = blockIdx.x * 256 + threadIdx.x;
    if (i < N) cnt[i] = 0;                       // replaces hipMemsetAsync
    if (i < 512 * 160) {                         // node: tp 0..31, k4 0..4 (K=160)
        int j = i & 7, unit = i >> 3;
        int lane = unit & 63, tk = unit >> 6;
        int tp = tk / 5, k4 = tk - tp * 5;
        int r = (tp & 3) * 128 + (tp >> 2) * 16 + (lane & 15);   // u-repacked row
        int k = k4 * 32 + (lane >> 4) * 8 + j;
        float v = (k < 128) ? Whh_n[r * 128 + k]
                : (k < 133) ? Wih_n[r * 5 + (k - 128)]
                : (k == 133) ? (bih_n[r] + bhh_n[r]) : 0.f;
        WnF[i] = (unsigned short)bfr(v);
    }
    if (i < 128 * 64) {                          // edge: t 0..7, s 0..1 (K=64)
        int j = i & 7, unit = i >> 3;
        int lane = unit & 63, ts = unit >> 6;
        int t = ts >> 1, s = ts & 1;
        int r = t * 16 + (lane & 15);
        int k = s * 32 + (lane >> 4) * 8 + j;
        float v = (k < 32) ? Whh_e[r * 32 + k]
                : (k < 34) ? Wih_e[r * 2 + (k - 32)]
                : (k == 34) ? (bih_e[r] + bhh_e[r]) : 0.f;
        WeF[i] = (unsigned short)bfr(v);
    }
    if (i < 64 * 160) {                          // gat (W^T): t 0..3, k4 0..4
        int j = i & 7, unit = i >> 3;
        int lane = unit & 63, tk = unit >> 6;
        int t = tk / 5, k4 = tk - t * 5;
        int r = t * 16 + (lane & 15);
        int k = k4 * 32 + (lane >> 4) * 8 + j;
        WgF[i] = (unsigned short)bfr(Wgat[k * 64 + r]);
    }
}

// ---------------- capped per-dst slot list build: stores (edge, src) pairs ----------------
__global__ void csr_fill_kernel(const int* __restrict__ src, const int* __restrict__ dst,
                                int* __restrict__ cnt, int2* __restrict__ eidp, int E)
{
    int e = blockIdx.x * blockDim.x + threadIdx.x;
    if (e >= E) return;
    int d = dst[e];
    int s = src[e];
    int k = atomicAdd(cnt + d, 1);
    if (k < CAP) eidp[(size_t)d * CAP + k] = make_int2(e, s);
}

// ---------------- edge LSTM v5: packed linear streams + persistent grid-stride pipeline ----------------
__global__ __launch_bounds__(256, 3) void edge_lstm_mfma(
    const float* __restrict__ eattr, const float* __restrict__ h_in, const float* __restrict__ c_in,
    const unsigned short* __restrict__ WeF,
    float* __restrict__ he_out, float* __restrict__ ce_out, int E)
{
    __shared__ float Gall[4][16 * 132];              // per-wave gate buffer [edge][128] (+pad)
    __shared__ unsigned short Hall[4][16 * 40];      // per-wave bf16 h tile, row stride 40
    const int lane = threadIdx.x & 63, wave = threadIdx.x >> 6;
    const int lr = lane & 15, lg = lane >> 4;
    const int T = E >> 4;                            // E % 16 == 0
    const int nwaves = gridDim.x * 4;
    const int wid = blockIdx.x * 4 + wave;
    if (wid >= T) return;
    float* G = Gall[wave];
    unsigned short* H = Hall[wave];

    const bf16x8* Wv = (const bf16x8*)WeF;
    bf16x8 wa0[8], wa1[8];
    #pragma unroll
    for (int t = 0; t < 8; ++t) {
        wa0[t] = Wv[(t * 2 + 0) * 64 + lane];
        wa1[t] = Wv[(t * 2 + 1) * 64 + lane];
    }

    f32x4 phA, phB, pcA, pcB; float pea0 = 0.f, pea1 = 0.f;
    {
        const size_t dwb = (size_t)wid * 512;
        phA = *(const f32x4*)(h_in + dwb + lane * 4);
        phB = *(const f32x4*)(h_in + dwb + 256 + lane * 4);
        pcA = *(const f32x4*)(c_in + dwb + lane * 4);
        pcB = *(const f32x4*)(c_in + dwb + 256 + lane * 4);
        if (lg == 0) {
            pea0 = eattr[(size_t)(wid * 16 + lr) * 2];
            pea1 = eattr[(size_t)(wid * 16 + lr) * 2 + 1];
        }
    }

    for (int t = wid; t < T; t += nwaves) {
        const f32x4 hA = phA, hB = phB, cA = pcA, cB = pcB;
        const float ea0 = pea0, ea1 = pea1;
        const size_t dwbase = (size_t)t * 512;
        const int tn = t + nwaves;
        if (tn < T) {                                // issue next tile's loads NOW
            const size_t dwb = (size_t)tn * 512;
            phA = *(const f32x4*)(h_in + dwb + lane * 4);
            phB = *(const f32x4*)(h_in + dwb + 256 + lane * 4);
            pcA = *(const f32x4*)(c_in + dwb + lane * 4);
            pcB = *(const f32x4*)(c_in + dwb + 256 + lane * 4);
            if (lg == 0) {
                pea0 = eattr[(size_t)(tn * 16 + lr) * 2];
                pea1 = eattr[(size_t)(tn * 16 + lr) * 2 + 1];
            }
        }

        {
            const int e = lane >> 3, c4 = (lane & 7) * 4;
            ushort4 pa, pb;
            pa.x = (unsigned short)bfr(hA[0]); pa.y = (unsigned short)bfr(hA[1]);
            pa.z = (unsigned short)bfr(hA[2]); pa.w = (unsigned short)bfr(hA[3]);
            pb.x = (unsigned short)bfr(hB[0]); pb.y = (unsigned short)bfr(hB[1]);
            pb.z = (unsigned short)bfr(hB[2]); pb.w = (unsigned short)bfr(hB[3]);
            *(ushort4*)(H + e * 40 + c4)       = pa;     // rows 0-7
            *(ushort4*)(H + (8 + e) * 40 + c4) = pb;     // rows 8-15
        }
        bf16x8 b0 = *(const bf16x8*)(H + lr * 40 + lg * 8);
        bf16x8 b1 = {0,0,0,0,0,0,0,0};
        if (lg == 0) {                               // k=32,33 -> eattr; k=34 -> 1 (bias col)
            b1[0] = bfr(ea0); b1[1] = bfr(ea1); b1[2] = (short)0x3F80;
        }

        f32x4 acc[8];
        #pragma unroll
        for (int tt = 0; tt < 8; ++tt) {
            f32x4 v = {0, 0, 0, 0};
            v = __builtin_amdgcn_mfma_f32_16x16x32_bf16(wa0[tt], b0, v, 0, 0, 0);
            v = __builtin_amdgcn_mfma_f32_16x16x32_bf16(wa1[tt], b1, v, 0, 0, 0);
            acc[tt] = v;
        }

        #pragma unroll
        for (int u = 0; u < 8; ++u) {
            const int col = (u >> 1) * 32 + (u & 1) * 16 + lg * 4;
            *(f32x4*)(G + lr * 132 + col) = acc[u];
        }

        const int e = lane >> 3, jq = (lane & 7) * 4;
        #pragma unroll
        for (int part = 0; part < 2; ++part) {
            const float* gr = G + (part * 8 + e) * 132;
            const f32x4 gi = *(const f32x4*)(gr + jq);
            const f32x4 gf = *(const f32x4*)(gr + 32 + jq);
            const f32x4 gg = *(const f32x4*)(gr + 64 + jq);
            const f32x4 go = *(const f32x4*)(gr + 96 + jq);
            const f32x4 cold = part ? cB : cA;
            f32x4 cres, hres;
            #pragma unroll
            for (int q = 0; q < 4; ++q) {
                float c2 = sigf(gf[q]) * cold[q] + sigf(gi[q]) * tanhfast(gg[q]);
                cres[q] = c2;
                hres[q] = sigf(go[q]) * tanhfast(c2);
            }
            __builtin_nontemporal_store(cres, (f32x4*)(ce_out + dwbase + part * 256 + lane * 4));
            *(f32x4*)(he_out + dwbase + part * 256 + lane * 4) = hres;   // re-read by enc gather
        }
    }
}

// ---------------- node LSTM via MFMA: wave = 16 nodes, K=160, u-repacked (4 live accs) ----------------
__global__ __launch_bounds__(256) void node_lstm_mfma(
    const float* __restrict__ x, const float* __restrict__ h_in, const float* __restrict__ c_in,
    const unsigned short* __restrict__ WnF,
    float* __restrict__ hn_out, float* __restrict__ cn_out, int N)
{
    const int lane = threadIdx.x & 63, wave = threadIdx.x >> 6;
    const int nbase = blockIdx.x * 64 + wave * 16;
    if (nbase >= N) return;                      // N % 16 == 0
    const int lr = lane & 15, lg = lane >> 4;
    const int node = nbase + lr;
    bf16x8 b[5];
    const float* hp = h_in + (size_t)node * 128 + lg * 8;
    b[0] = cvt8(hp); b[1] = cvt8(hp + 32); b[2] = cvt8(hp + 64); b[3] = cvt8(hp + 96);
    bf16x8 bx = {0,0,0,0,0,0,0,0};
    if (lg == 0) {                               // k=128..132 -> x; k=133 -> 1 (bias col)
        const float* xp = x + (size_t)node * 5;
        bx[0]=bfr(xp[0]); bx[1]=bfr(xp[1]); bx[2]=bfr(xp[2]); bx[3]=bfr(xp[3]); bx[4]=bfr(xp[4]);
        bx[5] = (short)0x3F80;
    }
    b[4] = bx;
    const bf16x8* Wv = (const bf16x8*)WnF;
    #pragma unroll
    for (int u = 0; u < 8; ++u) {                // only 4 live accumulators per u-block
        f32x4 acc[4];
        #pragma unroll
        for (int g = 0; g < 4; ++g) {
            const bf16x8* ap = Wv + (u * 4 + g) * 320 + lane;
            f32x4 v = {0, 0, 0, 0};
            #pragma unroll
            for (int k4 = 0; k4 < 5; ++k4)
                v = __builtin_amdgcn_mfma_f32_16x16x32_bf16(ap[k4 * 64], b[k4], v, 0, 0, 0);
            acc[g] = v;
        }
        const int jb = u * 16 + lg * 4;
        f32x4 cold = *(const f32x4*)(c_in + (size_t)node * 128 + jb);
        f32x4 cres, hres;
        #pragma unroll
        for (int q = 0; q < 4; ++q) {
            float c2 = sigf(acc[1][q]) * cold[q] + sigf(acc[0][q]) * tanhfast(acc[2][q]);
            cres[q] = c2;
            hres[q] = sigf(acc[3][q]) * tanhfast(c2);
        }
        __builtin_nontemporal_store(cres, (f32x4*)(cn_out + (size_t)node * 128 + jb));
        *(f32x4*)(hn_out + (size_t)node * 128 + jb) = hres;      // re-read by gat_xl
    }
}

// ---------------- fused edge_enc (LDS-only) + GAT linear: block = 64 nodes ----------------
__global__ __launch_bounds__(256) void enc_gatxl_kernel(
    const int* __restrict__ cnt, const int2* __restrict__ eidp, const float* __restrict__ he,
    const float* __restrict__ hn, const unsigned short* __restrict__ WgF,
    const float* __restrict__ attS, const float* __restrict__ attD,
    unsigned short* __restrict__ xlb, float* __restrict__ asrc, float* __restrict__ adst, int N)
{
    __shared__ float encs[64 * 36];              // row stride 36: 2-way max bank alias
    const int lane = threadIdx.x & 63, wave = threadIdx.x >> 6;
    const int nbase = blockIdx.x * 64 + wave * 16;
    if (nbase >= N) return;                      // N % 16 == 0 -> wave-uniform
    // ---- phase A: lanes 0-31 -> node t, lanes 32-63 -> node t+1 ----
    const int half = lane >> 5, hl = lane & 31;
    const int g4 = hl >> 3, l8 = hl & 7;         // 4 groups x 8 lanes x float4
    for (int t = 0; t < 16; t += 2) {
        const int node = nbase + t + half;
        const int c = cnt[node];
        const int m = min(c, CAP);
        const int2* el = eidp + (size_t)node * CAP;
        f32x4 acc = {0, 0, 0, 0};
        for (int i = g4; i < m; i += 4)
            acc += *(const f32x4*)(he + (size_t)el[i].x * 32 + l8 * 4);
        #pragma unroll
        for (int off = 8; off <= 16; off <<= 1) {    // reduce within 32-lane half
            acc[0] += __shfl_xor(acc[0], off);
            acc[1] += __shfl_xor(acc[1], off);
            acc[2] += __shfl_xor(acc[2], off);
            acc[3] += __shfl_xor(acc[3], off);
        }
        if (g4 == 0) {
            float inv = 1.0f / fmaxf((float)c, 1.0f);
            f32x4 r; r[0]=acc[0]*inv; r[1]=acc[1]*inv; r[2]=acc[2]*inv; r[3]=acc[3]*inv;
            *(f32x4*)(&encs[(wave * 16 + t + half) * 36 + l8 * 4]) = r;
        }
    }
    // ---- phase B (same wave consumes its own enc rows; no __syncthreads) ----
    const int lr = lane & 15, lg = lane >> 4;
    const int node = nbase + lr;
    bf16x8 b[5];
    const float* hp = hn + (size_t)node * 128 + lg * 8;
    b[0] = cvt8(hp); b[1] = cvt8(hp + 32); b[2] = cvt8(hp + 64); b[3] = cvt8(hp + 96);
    b[4] = cvt8(&encs[(wave * 16 + lr) * 36 + lg * 8]);
    const bf16x8* Wv = (const bf16x8*)WgF;
    #pragma unroll
    for (int t = 0; t < 4; ++t) {                // t = head
        const bf16x8* ap = Wv + t * 320 + lane;
        f32x4 v = {0, 0, 0, 0};
        #pragma unroll
        for (int k4 = 0; k4 < 5; ++k4)
            v = __builtin_amdgcn_mfma_f32_16x16x32_bf16(ap[k4 * 64], b[k4], v, 0, 0, 0);
        ushort4 pk;
        pk.x = (unsigned short)bfr(v[0]); pk.y = (unsigned short)bfr(v[1]);
        pk.z = (unsigned short)bfr(v[2]); pk.w = (unsigned short)bfr(v[3]);
        *(ushort4*)(xlb + (size_t)node * 64 + t * 16 + lg * 4) = pk;
        const f32x4 ws = *(const f32x4*)(attS + t * 16 + lg * 4);
        const f32x4 wd = *(const f32x4*)(attD + t * 16 + lg * 4);
        float p1 = v[0]*ws[0] + v[1]*ws[1] + v[2]*ws[2] + v[3]*ws[3];
        float p2 = v[0]*wd[0] + v[1]*wd[1] + v[2]*wd[2] + v[3]*wd[3];
        p1 += __shfl_xor(p1, 16); p2 += __shfl_xor(p2, 16);
        p1 += __shfl_xor(p1, 32); p2 += __shfl_xor(p2, 32);
        if (lg == 0) {
            asrc[(size_t)node * 4 + t] = p1;
            adst[(size_t)node * 4 + t] = p2;
        }
    }
}

// ---------------- fused GAT softmax + aggregation: one wave per node, bf16 xl ----------------
__global__ __launch_bounds__(256) void gat_node_kernel(
    const int* __restrict__ cnt, const int2* __restrict__ eidp,
    const float* __restrict__ asrc, const float* __restrict__ adst,
    const unsigned short* __restrict__ xlb, const float* __restrict__ bias,
    float* __restrict__ out, int N)
{
    const int wid = (blockIdx.x * blockDim.x + threadIdx.x) >> 6;
    const int lane = threadIdx.x & 63;
    if (wid >= N) return;
    const int n = wid;
    const int m = min(cnt[n], CAP);
    const int h = lane >> 4, c16 = lane & 15;
    const int nslot = (m + 15) >> 4;             // <= 4
    const float ad = adst[n * 4 + h];
    float aself = asrc[n * 4 + h] + ad;
    aself = aself > 0.f ? aself : 0.2f * aself;
    const int2* el = eidp + (size_t)n * CAP;
    int   ss[4];
    float aa[4];
    float mx = aself;
    #pragma unroll
    for (int k = 0; k < 4; ++k) {
        if (k >= nslot) break;
        int i = k * 16 + c16;
        if (i < m) {
            int s = el[i].y;                     // src directly from slot pair
            float a = asrc[s * 4 + h] + ad;
            a = a > 0.f ? a : 0.2f * a;
            ss[k] = s; aa[k] = a;
            mx = fmaxf(mx, a);
        } else { ss[k] = 0; aa[k] = -1e30f; }
    }
    #pragma unroll
    for (int off = 1; off < 16; off <<= 1) mx = fmaxf(mx, __shfl_xor(mx, off));
    float ea[4];
    float p = 0.f;
    #pragma unroll
    for (int k = 0; k < 4; ++k) {
        if (k >= nslot) break;
        ea[k] = __expf(aa[k] - mx);
        p += ea[k];
    }
    #pragma unroll
    for (int off = 1; off < 16; off <<= 1) p += __shfl_xor(p, off);
    float eself = __expf(aself - mx);
    float sacc = eself + p;
    float oacc = eself * bf2f(xlb[(size_t)n * 64 + lane]);
    const int grp = lane & 48;
    #pragma unroll
    for (int k = 0; k < 4; ++k) {
        if (k >= nslot) break;
        const int lim = min(16, m - k * 16);
        #pragma unroll 8
        for (int cc = 0; cc < lim; ++cc) {       // 8 independent row loads in flight
            int srcl = grp | cc;
            float w = __shfl(ea[k], srcl);
            int   s = __shfl(ss[k], srcl);
            oacc += w * bf2f(xlb[(size_t)s * 64 + lane]);
        }
    }
    float r = oacc / sacc;
    r += __shfl_xor(r, 16);                      // head mean
    r += __shfl_xor(r, 32);
    if (lane < 16) out[(size_t)n * 16 + lane] = 0.25f * r + bias[lane];
}

extern "C" void kernel_launch(void* const* d_in, const int* in_sizes, int n_in,
                              void* d_out, int out_size, void* d_ws, size_t ws_size,
                              hipStream_t stream)
{
    const float* x     = (const float*)d_in[0];
    const int*   ei    = (const int*)  d_in[1];
    const float* eattr = (const float*)d_in[2];
    const float* hn_h  = (const float*)d_in[3];
    const float* hn_c  = (const float*)d_in[4];
    const float* he_h  = (const float*)d_in[5];
    const float* he_c  = (const float*)d_in[6];
    const float* Wih_n = (const float*)d_in[7];
    const float* Whh_n = (const float*)d_in[8];
    const float* bih_n = (const float*)d_in[9];
    const float* bhh_n = (const float*)d_in[10];
    const float* Wih_e = (const float*)d_in[11];
    const float* Whh_e = (const float*)d_in[12];
    const float* bih_e = (const float*)d_in[13];
    const float* bhh_e = (const float*)d_in[14];
    const float* W_gat = (const float*)d_in[15];
    const float* attS  = (const float*)d_in[16];
    const float* attD  = (const float*)d_in[17];
    const float* biasG = (const float*)d_in[18];

    const int N = in_sizes[0] / 5;
    const int E = in_sizes[2] / 2;

    float* out = (float*)d_out;
    float* hn  = out + (size_t)N * 16;
    float* cn  = hn  + (size_t)N * 128;
    float* he  = cn  + (size_t)N * 128;
    float* ce  = he  + (size_t)E * 32;

    char* p = (char*)d_ws;
    size_t off = 0;
    auto take = [&](size_t bytes) -> void* {
        void* r = p + off;
        off = (off + bytes + 255) & ~(size_t)255;
        return r;
    };
    int*   cnt  = (int*)  take((size_t)N * 4);
    int2*  eidp = (int2*) take((size_t)N * CAP * 8);
    unsigned short* xlb = (unsigned short*)take((size_t)N * 64 * 2);
    float* asrc = (float*)take((size_t)N * 4 * 4);
    float* adst = (float*)take((size_t)N * 4 * 4);
    unsigned short* WnF = (unsigned short*)take(512 * 160 * 2);
    unsigned short* WeF = (unsigned short*)take(128 * 64 * 2);
    unsigned short* WgF = (unsigned short*)take(64 * 160 * 2);

    convert_kernel<<<(512 * 160 + 255) / 256, 256, 0, stream>>>(
        Whh_n, Wih_n, bih_n, bhh_n, Whh_e, Wih_e, bih_e, bhh_e, W_gat,
        WnF, WeF, WgF, cnt, N);
    csr_fill_kernel<<<(E + 255) / 256, 256, 0, stream>>>(ei, ei + E, cnt, eidp, E);
    edge_lstm_mfma<<<768, 256, 0, stream>>>(
        eattr, he_h, he_c, WeF, he, ce, E);
    node_lstm_mfma<<<(N + 63) / 64, 256, 0, stream>>>(
        x, hn_h, hn_c, WnF, hn, cn, N);
    enc_gatxl_kernel<<<(N + 63) / 64, 256, 0, stream>>>(
        cnt, eidp, he, hn, WgF, attS, attD, xlb, asrc, adst, N);
    gat_node_kernel<<<(N + 3) / 4, 256, 0, stream>>>(
        cnt, eidp, asrc, adst, xlb, biasG, out, N);
}